// Round 7
// baseline (195.819 us; speedup 1.0000x reference)
//
#include <hip/hip_runtime.h>
#include <math.h>

#define B_TOTAL 2048
#define I_TOTAL 2048
#define O_TOTAL 2048
#define KW 64
#define NIN 6
#define BLOCK 256
#define TILE_B 16
#define CHB 4                       // b's per staging round = ds_read_b128 width
#define ROUNDS (TILE_B / CHB)       /* 4   */
#define BBLOCKS (B_TOTAL / TILE_B)  /* 128 */
#define OBLOCKS (O_TOTAL / BLOCK)   /* 8   */

typedef __attribute__((ext_vector_type(2))) float f2;
typedef __attribute__((ext_vector_type(4))) float f4;

// ws layout:
//   wP   [32][O] f2 {base=sig(t[2j]), diff=sig(t[2j+1])-sig(t[2j])}  512 KB
//   m32T [6][O]  int32                                                48 KB
#define WS_WP  0
#define WS_M32 (32 * O_TOTAL * sizeof(f2))

// Prep: pair-leaf sigmoid weights in [j][o] layout (coalesced dwordx2 loads),
// mapping int64/int32 auto-detected -> transposed int32 m32T[i][o].
__global__ void prep_kernel(const float* __restrict__ table,
                            const unsigned int* __restrict__ map_raw,
                            f2* __restrict__ wP,
                            int* __restrict__ m32T)
{
    int idx = blockIdx.x * blockDim.x + threadIdx.x;   // 0 .. O*32-1
    int o = idx >> 5, j = idx & 31;
    float s0 = 1.0f / (1.0f + __expf(-table[o * KW + 2 * j]));
    float s1 = 1.0f / (1.0f + __expf(-table[o * KW + 2 * j + 1]));
    f2 v; v.x = s0; v.y = s1 - s0;
    wP[j * O_TOTAL + o] = v;

    if (idx < O_TOTAL * NIN) {
        // int64 little-endian, values < 2048 => odd u32 words all zero.
        bool is64 = ((map_raw[1] | map_raw[3] | map_raw[5] | map_raw[7]) == 0u);
        int val = is64 ? (int)map_raw[2 * idx] : (int)map_raw[idx];
        int oo = idx / NIN, ii = idx - oo * NIN;
        m32T[ii * O_TOTAL + oo] = val;
    }
}

__device__ __forceinline__ f2 bc(float s) { f2 r; r.x = s; r.y = s; return r; }

// depth-first multilinear tree over a packed b-PAIR (v_pk_fma_f32).
// Per-component ops identical to the scalar tree -> bit-identical results.
__device__ __forceinline__ f2 tree6(const f2* __restrict__ ww, const f2 xv[NIN])
{
    f2 a5[2];
    #pragma unroll
    for (int h5 = 0; h5 < 2; ++h5) {
        f2 a4[2];
        #pragma unroll
        for (int h4 = 0; h4 < 2; ++h4) {
            f2 a3[2];
            #pragma unroll
            for (int h3 = 0; h3 < 2; ++h3) {
                f2 a2[2];
                #pragma unroll
                for (int h2 = 0; h2 < 2; ++h2) {
                    f2 a1[2];
                    #pragma unroll
                    for (int h1 = 0; h1 < 2; ++h1) {
                        int j = (((h5 * 2 + h4) * 2 + h3) * 2 + h2) * 2 + h1;
                        f2 w = ww[j];
                        a1[h1] = __builtin_elementwise_fma(xv[0], bc(w.y), bc(w.x));
                    }
                    a2[h2] = __builtin_elementwise_fma(xv[1], a1[1] - a1[0], a1[0]);
                }
                a3[h3] = __builtin_elementwise_fma(xv[2], a2[1] - a2[0], a2[0]);
            }
            a4[h4] = __builtin_elementwise_fma(xv[3], a3[1] - a3[0], a3[0]);
        }
        a5[h5] = __builtin_elementwise_fma(xv[4], a4[1] - a4[0], a4[0]);
    }
    return __builtin_elementwise_fma(xv[5], a5[1] - a5[0], a5[0]);
}

// Main: lanes over o. LDS staged B-MINOR: xs[idx] = 4 consecutive b's of one
// index -> the 6-way random gather is ds_read_b128 (4 b's per instr, banks
// 4*(m%8): ~13 bank-cyc vs 8 ideal) instead of 4x random b32 (~16 cyc each).
// Gather wave count drops 4x; tree is pk-packed over b-pairs.
__global__ __launch_bounds__(BLOCK, 4) void lut_main(
    const float* __restrict__ x,
    const f2*    __restrict__ wP,
    const int*   __restrict__ m32T,
    float*       __restrict__ out)
{
    __shared__ f4 xs[I_TOTAL];          // 32 KB: [idx] -> {b0,b0+1,b0+2,b0+3}

    const int o  = blockIdx.y * BLOCK + threadIdx.x;
    const int b0 = blockIdx.x * TILE_B;

    f2 ww[32];                          // 64 VGPRs, persist across rounds
    #pragma unroll
    for (int j = 0; j < 32; ++j) ww[j] = wP[j * O_TOTAL + o];

    int m[NIN];
    #pragma unroll
    for (int i = 0; i < NIN; ++i) m[i] = m32T[i * O_TOTAL + o];

    for (int r = 0; r < ROUNDS; ++r) {
        __syncthreads();
        // stage 4 b-rows, b-minor: 4 coalesced dword loads + 1 ds_write_b128
        // (lane word-stride 4 -> exactly 8 words/bank: conflict-free minimum)
        const float* xb = x + (size_t)(b0 + r * CHB) * I_TOTAL;
        #pragma unroll
        for (int t = 0; t < I_TOTAL / BLOCK; ++t) {    // 8 iters
            int idx = t * BLOCK + threadIdx.x;
            f4 v;
            v.x = xb[idx];
            v.y = xb[I_TOTAL + idx];
            v.z = xb[2 * I_TOTAL + idx];
            v.w = xb[3 * I_TOTAL + idx];
            xs[idx] = v;
        }
        __syncthreads();

        f4 q[NIN];
        #pragma unroll
        for (int i = 0; i < NIN; ++i) q[i] = xs[m[i]];   // ds_read_b128 gather

        f2 xlo[NIN], xhi[NIN];
        #pragma unroll
        for (int i = 0; i < NIN; ++i) {
            xlo[i].x = q[i].x; xlo[i].y = q[i].y;
            xhi[i].x = q[i].z; xhi[i].y = q[i].w;
        }
        f2 rlo = tree6(ww, xlo);
        f2 rhi = tree6(ww, xhi);

        float* op = out + (size_t)(b0 + r * CHB) * O_TOTAL + o;  // coalesced
        op[0 * O_TOTAL] = rlo.x;
        op[1 * O_TOTAL] = rlo.y;
        op[2 * O_TOTAL] = rhi.x;
        op[3 * O_TOTAL] = rhi.y;
    }
}

extern "C" void kernel_launch(void* const* d_in, const int* in_sizes, int n_in,
                              void* d_out, int out_size, void* d_ws, size_t ws_size,
                              hipStream_t stream)
{
    const float*        x       = (const float*)d_in[0];
    const float*        table   = (const float*)d_in[1];
    const unsigned int* map_raw = (const unsigned int*)d_in[2];
    float* out  = (float*)d_out;
    f2*    wP   = (f2*) ((char*)d_ws + WS_WP);
    int*   m32T = (int*)((char*)d_ws + WS_M32);

    prep_kernel<<<(O_TOTAL * 32) / BLOCK, BLOCK, 0, stream>>>(table, map_raw, wP, m32T);

    // grid x = b-block (fast dim): the 8 o-blocks sharing a b-block's x rows
    // land on the same XCD (128 % 8 == 0) -> staged x reads are L2-hot.
    dim3 grid(BBLOCKS, OBLOCKS);
    lut_main<<<grid, dim3(BLOCK), 0, stream>>>(x, wP, m32T, out);
}